// Round 2
// baseline (840.460 us; speedup 1.0000x reference)
//
#include <hip/hip_runtime.h>
#include <cstdint>

using bf16x8 = __attribute__((ext_vector_type(8))) __bf16;
using f32x4  = __attribute__((ext_vector_type(4))) float;
using s16x8  = __attribute__((ext_vector_type(8))) short;
using s16x4  = __attribute__((ext_vector_type(4))) short;

#define DI static __device__ __forceinline__

DI short f2bf(float f) {
  unsigned u = __float_as_uint(f);
  u = (u + 0x7fffu + ((u >> 16) & 1u)) >> 16;
  return (short)u;
}
DI float bf2f(short s) {
  return __uint_as_float(((unsigned)(unsigned short)s) << 16);
}

DI void gload16(const short* g, short* l) {
  __builtin_amdgcn_global_load_lds((const __attribute__((address_space(1))) unsigned*)g,
                                   (__attribute__((address_space(3))) unsigned*)l, 16, 0, 0);
}

DI f32x4 mfma16(bf16x8 a, bf16x8 b, f32x4 c) {
  return __builtin_amdgcn_mfma_f32_16x16x32_bf16(a, b, c, 0, 0, 0);
}

// Stage 64 rows x 256 cols bf16 (row-major) into LDS with XOR-16B-chunk swizzle.
// LDS content: chunk c of row r holds global chunk (c ^ (r&7)) of row r.
// Read back chunk k as LDS chunk (k ^ (r&7)) -> conflict-free ds_read_b128.
DI void stage64(const short* __restrict__ G, short* As, int w, int lane) {
  int r2 = lane >> 5, c8 = lane & 31;
  #pragma unroll
  for (int i = 0; i < 8; ++i) {
    int seg = w * 8 + i;          // 2 rows per seg (1KB per wave-dispatch)
    int row = seg * 2 + r2;
    gload16(G + (size_t)row * 256 + ((c8 ^ (row & 7)) * 8), As + seg * 512);
  }
}

// ---------------- weight prep ----------------
__global__ void k_transpose(const float* __restrict__ src, short* __restrict__ dst,
                            int K, int N) {
  int idx = blockIdx.x * 256 + threadIdx.x;   // dst[n][k] = src[k][n]
  if (idx >= N * K) return;
  int n = idx / K, k = idx - n * K;
  dst[idx] = f2bf(src[(size_t)k * N + n]);
}

__global__ void k_prep_qkv(const float* __restrict__ w, const float* __restrict__ b,
                           short* __restrict__ wt, float* __restrict__ bp) {
  int idx = blockIdx.x * 256 + threadIdx.x;   // 768*256
  if (idx >= 768 * 256) return;
  int jn = idx >> 8;        // new col: q*256 + h*32 + d
  int k  = idx & 255;
  int q = jn >> 8, rest = jn & 255, h = rest >> 5, d = rest & 31;
  int jo = h * 96 + d * 3 + q;
  wt[idx] = f2bf(w[(size_t)k * 768 + jo]);
  if (k == 0) bp[jn] = b[jo];
}

// ---------------- QKV with fused LN1 + window gather ----------------
// One block per window (64 tokens). A resident in LDS; weights streamed from L2.
__global__ __launch_bounds__(256, 2) void k_qkvln(
    const float* __restrict__ x, const float* __restrict__ g1, const float* __restrict__ b1v,
    const short* __restrict__ WqkvT, const float* __restrict__ qbp,
    short* __restrict__ qkv, int win0, int mtot)
{
  __shared__ __align__(16) short As[64 * 256];
  const int tid = threadIdx.x, lane = tid & 63, w = tid >> 6;
  const int l15 = lane & 15, hi = lane >> 4, hi4 = hi * 4;
  const int wg = win0 + blockIdx.x;
  const int bb = wg >> 6, wl = wg & 63, wrr = wl >> 3, wcc = wl & 7;
  // LN1: each 16-lane group handles one row per pass (4 passes x 4 groups x 4 waves = 64)
  #pragma unroll
  for (int p = 0; p < 4; ++p) {
    int tok = w * 16 + p * 4 + hi;
    int sr = bb * 4096 + ((tok >> 3) * 8 + wrr) * 64 + (tok & 7) * 8 + wcc;
    const float* xr = x + (size_t)sr * 256;
    float4 v[4];
    #pragma unroll
    for (int ii = 0; ii < 4; ++ii) v[ii] = *(const float4*)(xr + l15 * 4 + ii * 64);
    float s = 0.f, q = 0.f;
    #pragma unroll
    for (int ii = 0; ii < 4; ++ii) {
      s += v[ii].x + v[ii].y + v[ii].z + v[ii].w;
      q += v[ii].x * v[ii].x + v[ii].y * v[ii].y + v[ii].z * v[ii].z + v[ii].w * v[ii].w;
    }
    #pragma unroll
    for (int mk = 1; mk < 16; mk <<= 1) { s += __shfl_xor(s, mk); q += __shfl_xor(q, mk); }
    float mean = s * (1.f / 256.f);
    float var  = q * (1.f / 256.f) - mean * mean;
    float rstd = rsqrtf(var + 1e-5f);
    #pragma unroll
    for (int ii = 0; ii < 4; ++ii) {
      float4 gv = *(const float4*)(g1 + l15 * 4 + ii * 64);
      float4 bv = *(const float4*)(b1v + l15 * 4 + ii * 64);
      s16x4 o;
      o[0] = f2bf((v[ii].x - mean) * rstd * gv.x + bv.x);
      o[1] = f2bf((v[ii].y - mean) * rstd * gv.y + bv.y);
      o[2] = f2bf((v[ii].z - mean) * rstd * gv.z + bv.z);
      o[3] = f2bf((v[ii].w - mean) * rstd * gv.w + bv.w);
      int c8 = (l15 >> 1) + ii * 8;
      *(s16x4*)(As + tok * 256 + ((c8 ^ (tok & 7)) << 3) + (l15 & 1) * 4) = o;
    }
  }
  __syncthreads();
  // three 256-col output regions: nc=0->Q(scaled), 1->K, 2->V
  for (int ncg = 0; ncg < 3; ++ncg) {
    f32x4 acc[4][4] = {};
    #pragma unroll
    for (int kk = 0; kk < 8; ++kk) {
      bf16x8 a[4], b[4];
      #pragma unroll
      for (int m = 0; m < 4; ++m) {
        int row = m * 16 + l15;
        a[m] = *(const bf16x8*)(As + row * 256 + (((kk * 4 + hi) ^ (row & 7)) << 3));
      }
      #pragma unroll
      for (int n = 0; n < 4; ++n) {
        int col = ncg * 256 + w * 64 + n * 16 + l15;
        b[n] = *(const bf16x8*)(WqkvT + (size_t)col * 256 + kk * 32 + hi * 8);
      }
      #pragma unroll
      for (int m = 0; m < 4; ++m)
        #pragma unroll
        for (int n = 0; n < 4; ++n) acc[m][n] = mfma16(a[m], b[n], acc[m][n]);
    }
    float sc = (ncg == 0) ? 0.17677669529663687f : 1.0f;
    short* dst = qkv + ((size_t)ncg * mtot + (size_t)blockIdx.x * 64) * 256;
    #pragma unroll
    for (int n = 0; n < 4; ++n) {
      int colb = w * 64 + n * 16 + l15;
      float bia = qbp[ncg * 256 + colb];
      #pragma unroll
      for (int m = 0; m < 4; ++m)
        #pragma unroll
        for (int j = 0; j < 4; ++j)
          dst[(size_t)(m * 16 + hi4 + j) * 256 + colb] = f2bf((acc[m][n][j] + bia) * sc);
    }
    dst += 0;
    #pragma unroll
    for (int n = 0; n < 4; ++n) { (void)n; }
    // advance rows: note row base folded into dst via blockIdx; per-m offset above
  }
}

// ---------------- window attention: one block per (window, head) ----------------
__global__ __launch_bounds__(256, 2) void k_attn(
    const short* __restrict__ Q, const short* __restrict__ Kb,
    const short* __restrict__ V, short* __restrict__ O)
{
  __shared__ __align__(16) short Ks[64 * 72];
  __shared__ __align__(16) short VT[32 * 72];
  __shared__ __align__(16) short Ps[64 * 72];
  const int head = blockIdx.x & 7, win = blockIdx.x >> 3;
  const int tid = threadIdx.x, lane = tid & 63, w = tid >> 6;
  const int l15 = lane & 15, hi = lane >> 4, hi4 = hi * 4;
  const size_t base = (size_t)win * 16384 + head * 32;
  {
    int kk = tid >> 2, db = (tid & 3) * 8;
    s16x8 kv = *(const s16x8*)(Kb + base + (size_t)kk * 256 + db);
    *(s16x8*)&Ks[kk * 72 + db] = kv;
    s16x8 vv = *(const s16x8*)(V + base + (size_t)kk * 256 + db);
    #pragma unroll
    for (int i = 0; i < 8; ++i) VT[(db + i) * 72 + kk] = vv[i];
  }
  bf16x8 aq = *(const bf16x8*)(Q + base + (size_t)(w * 16 + l15) * 256 + hi * 8);
  __syncthreads();
  f32x4 zero = {0.f, 0.f, 0.f, 0.f};
  f32x4 s[4];
  #pragma unroll
  for (int t = 0; t < 4; ++t) {
    bf16x8 bk = *(const bf16x8*)&Ks[(t * 16 + l15) * 72 + hi * 8];
    s[t] = mfma16(aq, bk, zero);
  }
  float rs[4];
  #pragma unroll
  for (int j = 0; j < 4; ++j) {
    float m = fmaxf(fmaxf(s[0][j], s[1][j]), fmaxf(s[2][j], s[3][j]));
    #pragma unroll
    for (int mk = 1; mk < 16; mk <<= 1) m = fmaxf(m, __shfl_xor(m, mk));
    float sum = 0.f;
    #pragma unroll
    for (int t = 0; t < 4; ++t) { float p = __expf(s[t][j] - m); s[t][j] = p; sum += p; }
    #pragma unroll
    for (int mk = 1; mk < 16; mk <<= 1) sum += __shfl_xor(sum, mk);
    rs[j] = 1.f / sum;
  }
  #pragma unroll
  for (int t = 0; t < 4; ++t)
    #pragma unroll
    for (int j = 0; j < 4; ++j)
      Ps[(w * 16 + hi4 + j) * 72 + t * 16 + l15] = f2bf(s[t][j]);
  __syncthreads();
  f32x4 o[2] = {{0.f,0.f,0.f,0.f}, {0.f,0.f,0.f,0.f}};
  #pragma unroll
  for (int ks = 0; ks < 2; ++ks) {
    bf16x8 ap = *(const bf16x8*)&Ps[(w * 16 + l15) * 72 + ks * 32 + hi * 8];
    #pragma unroll
    for (int dt = 0; dt < 2; ++dt) {
      bf16x8 bv = *(const bf16x8*)&VT[(dt * 16 + l15) * 72 + ks * 32 + hi * 8];
      o[dt] = mfma16(ap, bv, o[dt]);
    }
  }
  #pragma unroll
  for (int dt = 0; dt < 2; ++dt)
    #pragma unroll
    for (int j = 0; j < 4; ++j)
      O[(size_t)(win * 64 + w * 16 + hi4 + j) * 256 + head * 32 + dt * 16 + l15] =
          f2bf(o[dt][j] * rs[j]);
}

// ---------------- proj + residual + LN2: A-resident, weight-streaming ----------------
__global__ __launch_bounds__(256, 2) void k_proj(
    const short* __restrict__ ao, const short* __restrict__ WprojT,
    const float* __restrict__ pb, const float* __restrict__ x,
    short* __restrict__ y2, short* __restrict__ hresb,
    const float* __restrict__ g2, const float* __restrict__ b2, int chunk_off)
{
  __shared__ __align__(16) short As[64 * 256];
  __shared__ float redS[64 * 4];
  __shared__ float redQ[64 * 4];
  const int tid = threadIdx.x, lane = tid & 63, w = tid >> 6;
  const int l15 = lane & 15, hi = lane >> 4, hi4 = hi * 4;
  const int bm0 = blockIdx.x * 64;
  stage64(ao + (size_t)bm0 * 256, As, w, lane);
  __syncthreads();
  f32x4 acc[4][4] = {};
  #pragma unroll
  for (int kk = 0; kk < 8; ++kk) {
    bf16x8 a[4], b[4];
    #pragma unroll
    for (int m = 0; m < 4; ++m) {
      int row = m * 16 + l15;
      a[m] = *(const bf16x8*)(As + row * 256 + (((kk * 4 + hi) ^ (row & 7)) << 3));
    }
    #pragma unroll
    for (int n = 0; n < 4; ++n) {
      int col = w * 64 + n * 16 + l15;
      b[n] = *(const bf16x8*)(WprojT + (size_t)col * 256 + kk * 32 + hi * 8);
    }
    #pragma unroll
    for (int m = 0; m < 4; ++m)
      #pragma unroll
      for (int n = 0; n < 4; ++n) acc[m][n] = mfma16(a[m], b[n], acc[m][n]);
  }
  // epilogue: + bias + x residual (window->spatial), LN2 stats over 256 cols
  int srow[4][4];
  #pragma unroll
  for (int m = 0; m < 4; ++m)
    #pragma unroll
    for (int j = 0; j < 4; ++j) {
      int wrow = chunk_off + bm0 + m * 16 + hi4 + j;
      int bb = wrow >> 12, rem = wrow & 4095, win = rem >> 6, tok = rem & 63;
      int rsp = (tok >> 3) * 8 + (win >> 3);
      int csp = (tok & 7) * 8 + (win & 7);
      srow[m][j] = bb * 4096 + rsp * 64 + csp;
    }
  float s1[4][4] = {}, s2[4][4] = {};
  #pragma unroll
  for (int m = 0; m < 4; ++m)
    #pragma unroll
    for (int n = 0; n < 4; ++n) {
      int col = w * 64 + n * 16 + l15;
      float bia = pb[col];
      #pragma unroll
      for (int j = 0; j < 4; ++j) {
        float val = acc[m][n][j] + bia + x[(size_t)srow[m][j] * 256 + col];
        acc[m][n][j] = val;
        s1[m][j] += val; s2[m][j] += val * val;
      }
    }
  #pragma unroll
  for (int m = 0; m < 4; ++m)
    #pragma unroll
    for (int j = 0; j < 4; ++j) {
      float a = s1[m][j], bq = s2[m][j];
      #pragma unroll
      for (int mk = 1; mk < 16; mk <<= 1) { a += __shfl_xor(a, mk); bq += __shfl_xor(bq, mk); }
      s1[m][j] = a; s2[m][j] = bq;
    }
  if (l15 == 0) {
    #pragma unroll
    for (int m = 0; m < 4; ++m)
      #pragma unroll
      for (int j = 0; j < 4; ++j) {
        int rl = m * 16 + hi4 + j;
        redS[rl * 4 + w] = s1[m][j];
        redQ[rl * 4 + w] = s2[m][j];
      }
  }
  __syncthreads();
  #pragma unroll
  for (int m = 0; m < 4; ++m)
    #pragma unroll
    for (int j = 0; j < 4; ++j) {
      int rl = m * 16 + hi4 + j;
      float S = redS[rl * 4] + redS[rl * 4 + 1] + redS[rl * 4 + 2] + redS[rl * 4 + 3];
      float Qs = redQ[rl * 4] + redQ[rl * 4 + 1] + redQ[rl * 4 + 2] + redQ[rl * 4 + 3];
      float mean = S * (1.f / 256.f);
      float var  = Qs * (1.f / 256.f) - mean * mean;
      float rstd = rsqrtf(var + 1e-5f);
      int lrow = srow[m][j] - chunk_off;
      #pragma unroll
      for (int n = 0; n < 4; ++n) {
        int col = w * 64 + n * 16 + l15;
        float val = acc[m][n][j];
        hresb[(size_t)lrow * 256 + col] = f2bf(val);
        y2[(size_t)lrow * 256 + col] = f2bf((val - mean) * rstd * g2[col] + b2[col]);
      }
    }
}

// ---------------- fused MLP: out = hres + (gelu(y2@W1+b1))@W2 + b2 ----------------
__global__ __launch_bounds__(256, 2) void k_mlp(
    const short* __restrict__ y2, const short* __restrict__ hres,
    const short* __restrict__ W1T, const float* __restrict__ b1,
    const short* __restrict__ W2T, const float* __restrict__ b2,
    float* __restrict__ outp)
{
  __shared__ __align__(16) short As[64 * 256];
  __shared__ __align__(16) short hs[2][64 * 128];
  const int tid = threadIdx.x, lane = tid & 63, w = tid >> 6;
  const int l15 = lane & 15, hi = lane >> 4, hi4 = hi * 4;
  const int bm0 = blockIdx.x * 64;
  stage64(y2 + (size_t)bm0 * 256, As, w, lane);
  f32x4 oacc[4][4] = {};
  __syncthreads();
  for (int hc = 0; hc < 8; ++hc) {
    // phase 1: h-tile (64 x 128) = As @ W1T[hc]; waves split 4x32 h-cols
    f32x4 a1[4][2] = {};
    #pragma unroll
    for (int kk = 0; kk < 8; ++kk) {
      bf16x8 a[4], b[2];
      #pragma unroll
      for (int m = 0; m < 4; ++m) {
        int row = m * 16 + l15;
        a[m] = *(const bf16x8*)(As + row * 256 + (((kk * 4 + hi) ^ (row & 7)) << 3));
      }
      #pragma unroll
      for (int n2 = 0; n2 < 2; ++n2) {
        int hr = hc * 128 + w * 32 + n2 * 16 + l15;
        b[n2] = *(const bf16x8*)(W1T + (size_t)hr * 256 + kk * 32 + hi * 8);
      }
      #pragma unroll
      for (int m = 0; m < 4; ++m)
        #pragma unroll
        for (int n2 = 0; n2 < 2; ++n2) a1[m][n2] = mfma16(a[m], b[n2], a1[m][n2]);
    }
    // gelu -> bf16 -> hs (XOR-swizzled 16B chunks)
    short* hb = &hs[hc & 1][0];
    #pragma unroll
    for (int m = 0; m < 4; ++m)
      #pragma unroll
      for (int n2 = 0; n2 < 2; ++n2) {
        int colc = w * 32 + n2 * 16 + l15;
        float bia = b1[hc * 128 + colc];
        int c8 = colc >> 3, cin = colc & 7;
        #pragma unroll
        for (int j = 0; j < 4; ++j) {
          int row = m * 16 + hi4 + j;
          float vv = a1[m][n2][j] + bia;
          float ge = 0.5f * vv * (1.f + erff(vv * 0.70710678118654752f));
          hb[row * 128 + ((c8 ^ (row & 7)) << 3) + cin] = f2bf(ge);
        }
      }
    __syncthreads();
    // phase 2: oacc += hs @ W2T[:, hc*128..]; waves split 4x64 out-cols
    #pragma unroll
    for (int kk = 0; kk < 4; ++kk) {
      bf16x8 a[4], b[4];
      #pragma unroll
      for (int m = 0; m < 4; ++m) {
        int row = m * 16 + l15;
        a[m] = *(const bf16x8*)(hb + row * 128 + (((kk * 4 + hi) ^ (row & 7)) << 3));
      }
      #pragma unroll
      for (int n = 0; n < 4; ++n) {
        int nr = w * 64 + n * 16 + l15;
        b[n] = *(const bf16x8*)(W2T + (size_t)nr * 1024 + hc * 128 + kk * 32 + hi * 8);
      }
      #pragma unroll
      for (int m = 0; m < 4; ++m)
        #pragma unroll
        for (int n = 0; n < 4; ++n) oacc[m][n] = mfma16(a[m], b[n], oacc[m][n]);
    }
  }
  #pragma unroll
  for (int n = 0; n < 4; ++n) {
    int col = w * 64 + n * 16 + l15;
    float bia = b2[col];
    #pragma unroll
    for (int m = 0; m < 4; ++m)
      #pragma unroll
      for (int j = 0; j < 4; ++j) {
        size_t row = bm0 + m * 16 + hi4 + j;
        float hf = bf2f(hres[row * 256 + col]);
        outp[row * 256 + col] = hf + oacc[m][n][j] + bia;
      }
  }
}

// ---------------- host ----------------
extern "C" void kernel_launch(void* const* d_in, const int* in_sizes, int n_in,
                              void* d_out, int out_size, void* d_ws, size_t ws_size,
                              hipStream_t stream) {
  const float* x     = (const float*)d_in[0];
  const float* ln1g  = (const float*)d_in[1];
  const float* ln1b  = (const float*)d_in[2];
  const float* qkvw  = (const float*)d_in[3];
  const float* qkvb  = (const float*)d_in[4];
  const float* projw = (const float*)d_in[5];
  const float* projb = (const float*)d_in[6];
  const float* ln2g  = (const float*)d_in[7];
  const float* ln2b  = (const float*)d_in[8];
  const float* w1    = (const float*)d_in[9];
  const float* b1    = (const float*)d_in[10];
  const float* w2    = (const float*)d_in[11];
  const float* b2    = (const float*)d_in[12];
  float* out = (float*)d_out;
  char* ws = (char*)d_ws;

  const size_t MTOT = 131072;
  // choose chunk count by available workspace: per-chunk need = 4*M*512 B + ~2MB weights
  int nchunk;
  if (ws_size >= 4ull * MTOT * 512 + (2u << 20)) nchunk = 1;
  else if (ws_size >= 4ull * (MTOT / 2) * 512 + (2u << 20)) nchunk = 2;
  else nchunk = 4;
  const size_t M = MTOT / nchunk;
  const int nwin = (int)(M / 64);

  // ws layout: [qkv: 3*M*512 B][ao: M*512 B][weights ~1.6MB]
  // y2 aliases Q region, hres aliases K region (both dead after k_attn).
  short* qkv = (short*)ws;
  short* y2b = (short*)ws;
  short* hrb = (short*)ws + M * 256;
  short* aob = (short*)ws + 3 * M * 256;
  char*  wreg = ws + 4ull * M * 512;
  short* WqkvT  = (short*)wreg;                      // 393,216 B
  short* WprojT = (short*)(wreg + 393216);           // 131,072 B
  short* W1T    = (short*)(wreg + 524288);           // 524,288 B
  short* W2T    = (short*)(wreg + 1048576);          // 524,288 B
  float* qkvbp  = (float*)(wreg + 1572864);          // 3,072 B

  k_prep_qkv<<<768, 256, 0, stream>>>(qkvw, qkvb, WqkvT, qkvbp);
  k_transpose<<<256, 256, 0, stream>>>(projw, WprojT, 256, 256);
  k_transpose<<<1024, 256, 0, stream>>>(w1, W1T, 256, 1024);
  k_transpose<<<1024, 256, 0, stream>>>(w2, W2T, 1024, 256);

  for (int c = 0; c < nchunk; ++c) {
    k_qkvln<<<nwin, 256, 0, stream>>>(x, ln1g, ln1b, WqkvT, qkvbp, qkv,
                                      c * nwin, (int)M);
    k_attn<<<nwin * 8, 256, 0, stream>>>(qkv, qkv + M * 256, qkv + 2 * M * 256, aob);
    k_proj<<<nwin, 256, 0, stream>>>(aob, WprojT, projb, x, y2b, hrb,
                                     ln2g, ln2b, (int)(c * M));
    k_mlp<<<nwin, 256, 0, stream>>>(y2b, hrb, W1T, b1, W2T, b2,
                                    out + (size_t)c * M * 256);
  }
}

// Round 3
// 778.219 us; speedup vs baseline: 1.0800x; 1.0800x over previous
//
#include <hip/hip_runtime.h>
#include <cstdint>

using bf16x8 = __attribute__((ext_vector_type(8))) __bf16;
using f32x4  = __attribute__((ext_vector_type(4))) float;
using s16x8  = __attribute__((ext_vector_type(8))) short;
using s16x4  = __attribute__((ext_vector_type(4))) short;

#define DI static __device__ __forceinline__

DI short f2bf(float f) {
  unsigned u = __float_as_uint(f);
  u = (u + 0x7fffu + ((u >> 16) & 1u)) >> 16;
  return (short)u;
}
DI float bf2f(short s) {
  return __uint_as_float(((unsigned)(unsigned short)s) << 16);
}

DI void gload16(const short* g, short* l) {
  __builtin_amdgcn_global_load_lds((const __attribute__((address_space(1))) unsigned*)g,
                                   (__attribute__((address_space(3))) unsigned*)l, 16, 0, 0);
}

DI f32x4 mfma16(bf16x8 a, bf16x8 b, f32x4 c) {
  return __builtin_amdgcn_mfma_f32_16x16x32_bf16(a, b, c, 0, 0, 0);
}

// ---------------- weight prep ----------------
__global__ void k_transpose(const float* __restrict__ src, short* __restrict__ dst,
                            int K, int N) {
  int idx = blockIdx.x * 256 + threadIdx.x;   // dst[n][k] = src[k][n]
  if (idx >= N * K) return;
  int n = idx / K, k = idx - n * K;
  dst[idx] = f2bf(src[(size_t)k * N + n]);
}

__global__ void k_prep_qkv(const float* __restrict__ w, const float* __restrict__ b,
                           short* __restrict__ wt, float* __restrict__ bp) {
  int idx = blockIdx.x * 256 + threadIdx.x;   // 768*256
  if (idx >= 768 * 256) return;
  int jn = idx >> 8;        // new col: q*256 + h*32 + d
  int k  = idx & 255;
  int q = jn >> 8, rest = jn & 255, h = rest >> 5, d = rest & 31;
  int jo = h * 96 + d * 3 + q;
  wt[idx] = f2bf(w[(size_t)k * 768 + jo]);
  if (k == 0) bp[jn] = b[jo];
}

// ---------------- QKV with fused LN1 + window gather ----------------
// One block per window (64 tokens). A resident in LDS (XOR-swizzled);
// weights streamed from L2 with depth-2 rolling register prefetch.
__global__ __launch_bounds__(256, 4) void k_qkvln(
    const float* __restrict__ x, const float* __restrict__ g1, const float* __restrict__ b1v,
    const short* __restrict__ WqkvT, const float* __restrict__ qbp,
    short* __restrict__ qkv, int win0, int mtot)
{
  __shared__ __align__(16) short As[64 * 256];
  const int tid = threadIdx.x, lane = tid & 63, w = tid >> 6;
  const int l15 = lane & 15, hi = lane >> 4, hi4 = hi * 4;
  const int wg = win0 + blockIdx.x;
  const int bb = wg >> 6, wl = wg & 63, wrr = wl >> 3, wcc = wl & 7;
  // LN1: 16-lane group per row, 4 passes x 4 groups x 4 waves = 64 rows
  #pragma unroll
  for (int p = 0; p < 4; ++p) {
    int tok = w * 16 + p * 4 + hi;
    int sr = bb * 4096 + ((tok >> 3) * 8 + wrr) * 64 + (tok & 7) * 8 + wcc;
    const float* xr = x + (size_t)sr * 256;
    float4 v[4];
    #pragma unroll
    for (int ii = 0; ii < 4; ++ii) v[ii] = *(const float4*)(xr + l15 * 4 + ii * 64);
    float s = 0.f, q = 0.f;
    #pragma unroll
    for (int ii = 0; ii < 4; ++ii) {
      s += v[ii].x + v[ii].y + v[ii].z + v[ii].w;
      q += v[ii].x * v[ii].x + v[ii].y * v[ii].y + v[ii].z * v[ii].z + v[ii].w * v[ii].w;
    }
    #pragma unroll
    for (int mk = 1; mk < 16; mk <<= 1) { s += __shfl_xor(s, mk); q += __shfl_xor(q, mk); }
    float mean = s * (1.f / 256.f);
    float var  = q * (1.f / 256.f) - mean * mean;
    float rstd = rsqrtf(var + 1e-5f);
    #pragma unroll
    for (int ii = 0; ii < 4; ++ii) {
      float4 gv = *(const float4*)(g1 + l15 * 4 + ii * 64);
      float4 bv = *(const float4*)(b1v + l15 * 4 + ii * 64);
      s16x4 o;
      o[0] = f2bf((v[ii].x - mean) * rstd * gv.x + bv.x);
      o[1] = f2bf((v[ii].y - mean) * rstd * gv.y + bv.y);
      o[2] = f2bf((v[ii].z - mean) * rstd * gv.z + bv.z);
      o[3] = f2bf((v[ii].w - mean) * rstd * gv.w + bv.w);
      int c8 = (l15 >> 1) + ii * 8;
      *(s16x4*)(As + tok * 256 + ((c8 ^ (tok & 7)) << 3) + (l15 & 1) * 4) = o;
    }
  }
  __syncthreads();
  // 6 passes x 128 cols; wave owns 32 cols (2 n-tiles) per pass
  #pragma unroll
  for (int p = 0; p < 6; ++p) {
    const int colb = p * 128 + w * 32 + l15;
    const short* B0 = WqkvT + (size_t)colb * 256 + hi * 8;
    bf16x8 bn[2][2];
    bn[0][0] = *(const bf16x8*)(B0);
    bn[0][1] = *(const bf16x8*)(B0 + 16 * 256);
    bn[1][0] = *(const bf16x8*)(B0 + 32);
    bn[1][1] = *(const bf16x8*)(B0 + 16 * 256 + 32);
    f32x4 acc[4][2] = {};
    #pragma unroll
    for (int kk = 0; kk < 8; ++kk) {
      bf16x8 bc0 = bn[kk & 1][0], bc1 = bn[kk & 1][1];
      if (kk + 2 < 8) {
        bn[kk & 1][0] = *(const bf16x8*)(B0 + (kk + 2) * 32);
        bn[kk & 1][1] = *(const bf16x8*)(B0 + 16 * 256 + (kk + 2) * 32);
      }
      #pragma unroll
      for (int m = 0; m < 4; ++m) {
        int row = m * 16 + l15;
        bf16x8 a = *(const bf16x8*)(As + row * 256 + (((kk * 4 + hi) ^ (row & 7)) << 3));
        acc[m][0] = mfma16(a, bc0, acc[m][0]);
        acc[m][1] = mfma16(a, bc1, acc[m][1]);
      }
    }
    const int ncg = p >> 1;
    const float sc = (ncg == 0) ? 0.17677669529663687f : 1.0f;
    short* dst = qkv + ((size_t)ncg * mtot + (size_t)blockIdx.x * 64) * 256;
    #pragma unroll
    for (int n2 = 0; n2 < 2; ++n2) {
      int col = p * 128 + w * 32 + n2 * 16 + l15;
      int c255 = col & 255;
      float bia = qbp[col];
      #pragma unroll
      for (int m = 0; m < 4; ++m)
        #pragma unroll
        for (int j = 0; j < 4; ++j)
          dst[(size_t)(m * 16 + hi4 + j) * 256 + c255] = f2bf((acc[m][n2][j] + bia) * sc);
    }
  }
}

// ---------------- window attention: one block per (window, head) ----------------
__global__ __launch_bounds__(256, 4) void k_attn(
    const short* __restrict__ Q, const short* __restrict__ Kb,
    const short* __restrict__ V, short* __restrict__ O)
{
  __shared__ __align__(16) short Ks[64 * 72];
  __shared__ __align__(16) short VT[32 * 72];
  __shared__ __align__(16) short Ps[64 * 72];
  const int head = blockIdx.x & 7, win = blockIdx.x >> 3;
  const int tid = threadIdx.x, lane = tid & 63, w = tid >> 6;
  const int l15 = lane & 15, hi = lane >> 4, hi4 = hi * 4;
  const size_t base = (size_t)win * 16384 + head * 32;
  {
    int kk = tid >> 2, db = (tid & 3) * 8;
    s16x8 kv = *(const s16x8*)(Kb + base + (size_t)kk * 256 + db);
    *(s16x8*)&Ks[kk * 72 + db] = kv;
    s16x8 vv = *(const s16x8*)(V + base + (size_t)kk * 256 + db);
    #pragma unroll
    for (int i = 0; i < 8; ++i) VT[(db + i) * 72 + kk] = vv[i];
  }
  bf16x8 aq = *(const bf16x8*)(Q + base + (size_t)(w * 16 + l15) * 256 + hi * 8);
  __syncthreads();
  f32x4 zero = {0.f, 0.f, 0.f, 0.f};
  f32x4 s[4];
  #pragma unroll
  for (int t = 0; t < 4; ++t) {
    bf16x8 bk = *(const bf16x8*)&Ks[(t * 16 + l15) * 72 + hi * 8];
    s[t] = mfma16(aq, bk, zero);
  }
  float rs[4];
  #pragma unroll
  for (int j = 0; j < 4; ++j) {
    float m = fmaxf(fmaxf(s[0][j], s[1][j]), fmaxf(s[2][j], s[3][j]));
    #pragma unroll
    for (int mk = 1; mk < 16; mk <<= 1) m = fmaxf(m, __shfl_xor(m, mk));
    float sum = 0.f;
    #pragma unroll
    for (int t = 0; t < 4; ++t) { float p = __expf(s[t][j] - m); s[t][j] = p; sum += p; }
    #pragma unroll
    for (int mk = 1; mk < 16; mk <<= 1) sum += __shfl_xor(sum, mk);
    rs[j] = 1.f / sum;
  }
  #pragma unroll
  for (int t = 0; t < 4; ++t)
    #pragma unroll
    for (int j = 0; j < 4; ++j)
      Ps[(w * 16 + hi4 + j) * 72 + t * 16 + l15] = f2bf(s[t][j]);
  __syncthreads();
  f32x4 o[2] = {{0.f,0.f,0.f,0.f}, {0.f,0.f,0.f,0.f}};
  #pragma unroll
  for (int ks = 0; ks < 2; ++ks) {
    bf16x8 ap = *(const bf16x8*)&Ps[(w * 16 + l15) * 72 + ks * 32 + hi * 8];
    #pragma unroll
    for (int dt = 0; dt < 2; ++dt) {
      bf16x8 bv = *(const bf16x8*)&VT[(dt * 16 + l15) * 72 + ks * 32 + hi * 8];
      o[dt] = mfma16(ap, bv, o[dt]);
    }
  }
  #pragma unroll
  for (int dt = 0; dt < 2; ++dt)
    #pragma unroll
    for (int j = 0; j < 4; ++j)
      O[(size_t)(win * 64 + w * 16 + hi4 + j) * 256 + head * 32 + dt * 16 + l15] =
          f2bf(o[dt][j] * rs[j]);
}

// ---------------- proj + residual + LN2: A-resident, weight-streaming ----------------
__global__ __launch_bounds__(256, 4) void k_proj(
    const short* __restrict__ ao, const short* __restrict__ WprojT,
    const float* __restrict__ pb, const float* __restrict__ x,
    short* __restrict__ y2, short* __restrict__ hresb,
    const float* __restrict__ g2, const float* __restrict__ b2, int chunk_off)
{
  __shared__ __align__(16) short As[64 * 256];
  __shared__ float redS[64 * 4];
  __shared__ float redQ[64 * 4];
  const int tid = threadIdx.x, lane = tid & 63, w = tid >> 6;
  const int l15 = lane & 15, hi = lane >> 4, hi4 = hi * 4;
  const int bm0 = blockIdx.x * 64;
  {
    int r2 = lane >> 5, c8 = lane & 31;
    #pragma unroll
    for (int i = 0; i < 8; ++i) {
      int seg = w * 8 + i;
      int row = seg * 2 + r2;
      gload16(ao + (size_t)(bm0 + row) * 256 + ((c8 ^ (row & 7)) * 8), As + seg * 512);
    }
  }
  __syncthreads();
  const short* B0 = WprojT + (size_t)(w * 64 + l15) * 256 + hi * 8;
  bf16x8 bnx[4];
  #pragma unroll
  for (int n = 0; n < 4; ++n) bnx[n] = *(const bf16x8*)(B0 + n * 16 * 256);
  f32x4 acc[4][4] = {};
  #pragma unroll
  for (int kk = 0; kk < 8; ++kk) {
    bf16x8 bc[4] = {bnx[0], bnx[1], bnx[2], bnx[3]};
    if (kk < 7) {
      #pragma unroll
      for (int n = 0; n < 4; ++n)
        bnx[n] = *(const bf16x8*)(B0 + n * 16 * 256 + (kk + 1) * 32);
    }
    #pragma unroll
    for (int m = 0; m < 4; ++m) {
      int row = m * 16 + l15;
      bf16x8 a = *(const bf16x8*)(As + row * 256 + (((kk * 4 + hi) ^ (row & 7)) << 3));
      #pragma unroll
      for (int n = 0; n < 4; ++n) acc[m][n] = mfma16(a, bc[n], acc[m][n]);
    }
  }
  // epilogue: + bias + x residual (window->spatial), LN2 stats over 256 cols
  int srow[4][4];
  #pragma unroll
  for (int m = 0; m < 4; ++m)
    #pragma unroll
    for (int j = 0; j < 4; ++j) {
      int wrow = chunk_off + bm0 + m * 16 + hi4 + j;
      int bb = wrow >> 12, rem = wrow & 4095, win = rem >> 6, tok = rem & 63;
      int rsp = (tok >> 3) * 8 + (win >> 3);
      int csp = (tok & 7) * 8 + (win & 7);
      srow[m][j] = bb * 4096 + rsp * 64 + csp;
    }
  float s1[4][4] = {}, s2[4][4] = {};
  #pragma unroll
  for (int m = 0; m < 4; ++m)
    #pragma unroll
    for (int n = 0; n < 4; ++n) {
      int col = w * 64 + n * 16 + l15;
      float bia = pb[col];
      #pragma unroll
      for (int j = 0; j < 4; ++j) {
        float val = acc[m][n][j] + bia + x[(size_t)srow[m][j] * 256 + col];
        acc[m][n][j] = val;
        s1[m][j] += val; s2[m][j] += val * val;
      }
    }
  #pragma unroll
  for (int m = 0; m < 4; ++m)
    #pragma unroll
    for (int j = 0; j < 4; ++j) {
      float a = s1[m][j], bq = s2[m][j];
      #pragma unroll
      for (int mk = 1; mk < 16; mk <<= 1) { a += __shfl_xor(a, mk); bq += __shfl_xor(bq, mk); }
      s1[m][j] = a; s2[m][j] = bq;
    }
  if (l15 == 0) {
    #pragma unroll
    for (int m = 0; m < 4; ++m)
      #pragma unroll
      for (int j = 0; j < 4; ++j) {
        int rl = m * 16 + hi4 + j;
        redS[rl * 4 + w] = s1[m][j];
        redQ[rl * 4 + w] = s2[m][j];
      }
  }
  __syncthreads();
  #pragma unroll
  for (int m = 0; m < 4; ++m)
    #pragma unroll
    for (int j = 0; j < 4; ++j) {
      int rl = m * 16 + hi4 + j;
      float S = redS[rl * 4] + redS[rl * 4 + 1] + redS[rl * 4 + 2] + redS[rl * 4 + 3];
      float Qs = redQ[rl * 4] + redQ[rl * 4 + 1] + redQ[rl * 4 + 2] + redQ[rl * 4 + 3];
      float mean = S * (1.f / 256.f);
      float var  = Qs * (1.f / 256.f) - mean * mean;
      float rstd = rsqrtf(var + 1e-5f);
      int lrow = srow[m][j] - chunk_off;
      #pragma unroll
      for (int n = 0; n < 4; ++n) {
        int col = w * 64 + n * 16 + l15;
        float val = acc[m][n][j];
        hresb[(size_t)lrow * 256 + col] = f2bf(val);
        y2[(size_t)lrow * 256 + col] = f2bf((val - mean) * rstd * g2[col] + b2[col]);
      }
    }
}

// ---------------- fused MLP: out = hres + (gelu(y2@W1+b1))@W2 + b2 ----------------
// 512 threads, 8 waves. As 32KB + single-buffered hs 32KB -> 2 blocks/CU.
// 4 chunks of 256 h-cols; wave owns 32 h-cols (P1) / 32 out-cols (P2).
__global__ __launch_bounds__(512, 4) void k_mlp(
    const short* __restrict__ y2, const short* __restrict__ hres,
    const short* __restrict__ W1T, const float* __restrict__ b1,
    const short* __restrict__ W2T, const float* __restrict__ b2,
    float* __restrict__ outp)
{
  __shared__ __align__(16) short As[64 * 256];
  __shared__ __align__(16) short hs[64 * 256];
  const int tid = threadIdx.x, lane = tid & 63, w = tid >> 6;   // w in 0..7
  const int l15 = lane & 15, hi = lane >> 4, hi4 = hi * 4;
  const int bm0 = blockIdx.x * 64;
  {
    int r2 = lane >> 5, c8 = lane & 31;
    #pragma unroll
    for (int i = 0; i < 4; ++i) {
      int seg = w * 4 + i;
      int row = seg * 2 + r2;
      gload16(y2 + (size_t)(bm0 + row) * 256 + ((c8 ^ (row & 7)) * 8), As + seg * 512);
    }
  }
  f32x4 oacc[4][2] = {};
  __syncthreads();
  for (int hc = 0; hc < 4; ++hc) {
    // ---- P1: h-slice (64 x 256) cols hc*256.. ; wave cols w*32..+32
    const short* B1 = W1T + (size_t)(hc * 256 + w * 32 + l15) * 256 + hi * 8;
    bf16x8 p1[2][2];
    p1[0][0] = *(const bf16x8*)(B1);
    p1[0][1] = *(const bf16x8*)(B1 + 16 * 256);
    p1[1][0] = *(const bf16x8*)(B1 + 32);
    p1[1][1] = *(const bf16x8*)(B1 + 16 * 256 + 32);
    f32x4 acc1[4][2] = {};
    #pragma unroll
    for (int kk = 0; kk < 8; ++kk) {
      bf16x8 bc0 = p1[kk & 1][0], bc1 = p1[kk & 1][1];
      if (kk + 2 < 8) {
        p1[kk & 1][0] = *(const bf16x8*)(B1 + (kk + 2) * 32);
        p1[kk & 1][1] = *(const bf16x8*)(B1 + 16 * 256 + (kk + 2) * 32);
      }
      #pragma unroll
      for (int m = 0; m < 4; ++m) {
        int row = m * 16 + l15;
        bf16x8 a = *(const bf16x8*)(As + row * 256 + (((kk * 4 + hi) ^ (row & 7)) << 3));
        acc1[m][0] = mfma16(a, bc0, acc1[m][0]);
        acc1[m][1] = mfma16(a, bc1, acc1[m][1]);
      }
    }
    __syncthreads();   // previous P2 finished reading hs
    // gelu -> bf16 -> hs (XOR-swizzled 16B chunks)
    #pragma unroll
    for (int m = 0; m < 4; ++m)
      #pragma unroll
      for (int n2 = 0; n2 < 2; ++n2) {
        int col = w * 32 + n2 * 16 + l15;
        float bia = b1[hc * 256 + col];
        int c8 = col >> 3, cin = col & 7;
        #pragma unroll
        for (int j = 0; j < 4; ++j) {
          int row = m * 16 + hi4 + j;
          float vv = acc1[m][n2][j] + bia;
          float ge = 0.5f * vv * (1.f + erff(vv * 0.70710678118654752f));
          hs[row * 256 + ((c8 ^ (row & 7)) << 3) + cin] = f2bf(ge);
        }
      }
    __syncthreads();   // hs ready
    // ---- P2: oacc += hs(64x256) @ W2T k-slice; wave out-cols w*32..+32
    const short* B2 = W2T + (size_t)(w * 32 + l15) * 1024 + hc * 256 + hi * 8;
    bf16x8 p2[2][2];
    p2[0][0] = *(const bf16x8*)(B2);
    p2[0][1] = *(const bf16x8*)(B2 + 16 * 1024);
    p2[1][0] = *(const bf16x8*)(B2 + 32);
    p2[1][1] = *(const bf16x8*)(B2 + 16 * 1024 + 32);
    #pragma unroll
    for (int kk = 0; kk < 8; ++kk) {
      bf16x8 bc0 = p2[kk & 1][0], bc1 = p2[kk & 1][1];
      if (kk + 2 < 8) {
        p2[kk & 1][0] = *(const bf16x8*)(B2 + (kk + 2) * 32);
        p2[kk & 1][1] = *(const bf16x8*)(B2 + 16 * 1024 + (kk + 2) * 32);
      }
      #pragma unroll
      for (int m = 0; m < 4; ++m) {
        int row = m * 16 + l15;
        bf16x8 a = *(const bf16x8*)(hs + row * 256 + (((kk * 4 + hi) ^ (row & 7)) << 3));
        oacc[m][0] = mfma16(a, bc0, oacc[m][0]);
        oacc[m][1] = mfma16(a, bc1, oacc[m][1]);
      }
    }
  }
  #pragma unroll
  for (int n2 = 0; n2 < 2; ++n2) {
    int col = w * 32 + n2 * 16 + l15;
    float bia = b2[col];
    #pragma unroll
    for (int m = 0; m < 4; ++m)
      #pragma unroll
      for (int j = 0; j < 4; ++j) {
        size_t row = bm0 + m * 16 + hi4 + j;
        float hf = bf2f(hres[row * 256 + col]);
        outp[row * 256 + col] = hf + oacc[m][n2][j] + bia;
      }
  }
}

// ---------------- host ----------------
extern "C" void kernel_launch(void* const* d_in, const int* in_sizes, int n_in,
                              void* d_out, int out_size, void* d_ws, size_t ws_size,
                              hipStream_t stream) {
  const float* x     = (const float*)d_in[0];
  const float* ln1g  = (const float*)d_in[1];
  const float* ln1b  = (const float*)d_in[2];
  const float* qkvw  = (const float*)d_in[3];
  const float* qkvb  = (const float*)d_in[4];
  const float* projw = (const float*)d_in[5];
  const float* projb = (const float*)d_in[6];
  const float* ln2g  = (const float*)d_in[7];
  const float* ln2b  = (const float*)d_in[8];
  const float* w1    = (const float*)d_in[9];
  const float* b1    = (const float*)d_in[10];
  const float* w2    = (const float*)d_in[11];
  const float* b2    = (const float*)d_in[12];
  float* out = (float*)d_out;
  char* ws = (char*)d_ws;

  const size_t MTOT = 131072;
  int nchunk;
  if (ws_size >= 4ull * MTOT * 512 + (2u << 20)) nchunk = 1;
  else if (ws_size >= 4ull * (MTOT / 2) * 512 + (2u << 20)) nchunk = 2;
  else nchunk = 4;
  const size_t M = MTOT / nchunk;
  const int nwin = (int)(M / 64);

  short* qkv = (short*)ws;
  short* y2b = (short*)ws;
  short* hrb = (short*)ws + M * 256;
  short* aob = (short*)ws + 3 * M * 256;
  char*  wreg = ws + 4ull * M * 512;
  short* WqkvT  = (short*)wreg;                      // 393,216 B
  short* WprojT = (short*)(wreg + 393216);           // 131,072 B
  short* W1T    = (short*)(wreg + 524288);           // 524,288 B
  short* W2T    = (short*)(wreg + 1048576);          // 524,288 B
  float* qkvbp  = (float*)(wreg + 1572864);          // 3,072 B

  k_prep_qkv<<<768, 256, 0, stream>>>(qkvw, qkvb, WqkvT, qkvbp);
  k_transpose<<<256, 256, 0, stream>>>(projw, WprojT, 256, 256);
  k_transpose<<<1024, 256, 0, stream>>>(w1, W1T, 256, 1024);
  k_transpose<<<1024, 256, 0, stream>>>(w2, W2T, 1024, 256);

  for (int c = 0; c < nchunk; ++c) {
    k_qkvln<<<nwin, 256, 0, stream>>>(x, ln1g, ln1b, WqkvT, qkvbp, qkv,
                                      c * nwin, (int)M);
    k_attn<<<nwin * 8, 256, 0, stream>>>(qkv, qkv + M * 256, qkv + 2 * M * 256, aob);
    k_proj<<<nwin, 256, 0, stream>>>(aob, WprojT, projb, x, y2b, hrb,
                                     ln2g, ln2b, (int)(c * M));
    k_mlp<<<nwin, 512, 0, stream>>>(y2b, hrb, W1T, b1, W2T, b2,
                                    out + (size_t)c * M * 256);
  }
}

// Round 4
// 742.331 us; speedup vs baseline: 1.1322x; 1.0483x over previous
//
#include <hip/hip_runtime.h>
#include <cstdint>

using bf16x8 = __attribute__((ext_vector_type(8))) __bf16;
using f32x4  = __attribute__((ext_vector_type(4))) float;
using s16x8  = __attribute__((ext_vector_type(8))) short;
using s16x4  = __attribute__((ext_vector_type(4))) short;

#define DI static __device__ __forceinline__

DI short f2bf(float f) {
  unsigned u = __float_as_uint(f);
  u = (u + 0x7fffu + ((u >> 16) & 1u)) >> 16;
  return (short)u;
}
DI float bf2f(short s) {
  return __uint_as_float(((unsigned)(unsigned short)s) << 16);
}

DI void gload16(const short* g, short* l) {
  __builtin_amdgcn_global_load_lds((const __attribute__((address_space(1))) unsigned*)g,
                                   (__attribute__((address_space(3))) unsigned*)l, 16, 0, 0);
}

DI f32x4 mfma16(bf16x8 a, bf16x8 b, f32x4 c) {
  return __builtin_amdgcn_mfma_f32_16x16x32_bf16(a, b, c, 0, 0, 0);
}

// ---------------- weight prep ----------------
__global__ void k_transpose(const float* __restrict__ src, short* __restrict__ dst,
                            int K, int N) {
  int idx = blockIdx.x * 256 + threadIdx.x;   // dst[n][k] = src[k][n]
  if (idx >= N * K) return;
  int n = idx / K, k = idx - n * K;
  dst[idx] = f2bf(src[(size_t)k * N + n]);
}

__global__ void k_prep_qkv(const float* __restrict__ w, const float* __restrict__ b,
                           short* __restrict__ wt, float* __restrict__ bp) {
  int idx = blockIdx.x * 256 + threadIdx.x;   // 768*256
  if (idx >= 768 * 256) return;
  int jn = idx >> 8;        // new col: q*256 + h*32 + d
  int k  = idx & 255;
  int q = jn >> 8, rest = jn & 255, h = rest >> 5, d = rest & 31;
  int jo = h * 96 + d * 3 + q;
  wt[idx] = f2bf(w[(size_t)k * 768 + jo]);
  if (k == 0) bp[jn] = b[jo];
}

// ---------------- QKV with fused LN1 + window gather ----------------
// One block per window. A resident in LDS; weights streamed from L2 with
// depth-4 rolling register prefetch; swapped-operand MFMA -> b64 stores.
__global__ __launch_bounds__(256, 4) void k_qkvln(
    const float* __restrict__ x, const float* __restrict__ g1, const float* __restrict__ b1v,
    const short* __restrict__ WqkvT, const float* __restrict__ qbp,
    short* __restrict__ qkv, int win0, int mtot)
{
  __shared__ __align__(16) short As[64 * 256];
  const int tid = threadIdx.x, lane = tid & 63, w = tid >> 6;
  const int l15 = lane & 15, hi = lane >> 4, hi4 = hi * 4;
  const int wg = win0 + blockIdx.x;
  const int bb = wg >> 6, wl = wg & 63, wrr = wl >> 3, wcc = wl & 7;
  // LN1: 16-lane group per row
  #pragma unroll
  for (int p = 0; p < 4; ++p) {
    int tok = w * 16 + p * 4 + hi;
    int sr = bb * 4096 + ((tok >> 3) * 8 + wrr) * 64 + (tok & 7) * 8 + wcc;
    const float* xr = x + (size_t)sr * 256;
    float4 v[4];
    #pragma unroll
    for (int ii = 0; ii < 4; ++ii) v[ii] = *(const float4*)(xr + l15 * 4 + ii * 64);
    float s = 0.f, q = 0.f;
    #pragma unroll
    for (int ii = 0; ii < 4; ++ii) {
      s += v[ii].x + v[ii].y + v[ii].z + v[ii].w;
      q += v[ii].x * v[ii].x + v[ii].y * v[ii].y + v[ii].z * v[ii].z + v[ii].w * v[ii].w;
    }
    #pragma unroll
    for (int mk = 1; mk < 16; mk <<= 1) { s += __shfl_xor(s, mk); q += __shfl_xor(q, mk); }
    float mean = s * (1.f / 256.f);
    float var  = q * (1.f / 256.f) - mean * mean;
    float rstd = rsqrtf(var + 1e-5f);
    #pragma unroll
    for (int ii = 0; ii < 4; ++ii) {
      float4 gv = *(const float4*)(g1 + l15 * 4 + ii * 64);
      float4 bv = *(const float4*)(b1v + l15 * 4 + ii * 64);
      s16x4 o;
      o[0] = f2bf((v[ii].x - mean) * rstd * gv.x + bv.x);
      o[1] = f2bf((v[ii].y - mean) * rstd * gv.y + bv.y);
      o[2] = f2bf((v[ii].z - mean) * rstd * gv.z + bv.z);
      o[3] = f2bf((v[ii].w - mean) * rstd * gv.w + bv.w);
      int c8 = (l15 >> 1) + ii * 8;
      *(s16x4*)(As + tok * 256 + ((c8 ^ (tok & 7)) << 3) + (l15 & 1) * 4) = o;
    }
  }
  __syncthreads();
  // 6 passes x 128 cols; wave owns 32 cols
  #pragma unroll
  for (int p = 0; p < 6; ++p) {
    const short* B0 = WqkvT + (size_t)(p * 128 + w * 32 + l15) * 256 + hi * 8;
    bf16x8 pre[8];
    #pragma unroll
    for (int kp = 0; kp < 4; ++kp) {
      pre[kp * 2 + 0] = *(const bf16x8*)(B0 + kp * 32);
      pre[kp * 2 + 1] = *(const bf16x8*)(B0 + 16 * 256 + kp * 32);
    }
    f32x4 acc[4][2] = {};
    #pragma unroll
    for (int kk = 0; kk < 8; ++kk) {
      bf16x8 b0 = pre[(kk & 3) * 2], b1f = pre[(kk & 3) * 2 + 1];
      if (kk < 4) {
        pre[(kk & 3) * 2 + 0] = *(const bf16x8*)(B0 + (kk + 4) * 32);
        pre[(kk & 3) * 2 + 1] = *(const bf16x8*)(B0 + 16 * 256 + (kk + 4) * 32);
      }
      #pragma unroll
      for (int m = 0; m < 4; ++m) {
        int row = m * 16 + l15;
        bf16x8 a = *(const bf16x8*)(As + row * 256 + (((kk * 4 + hi) ^ (row & 7)) << 3));
        acc[m][0] = mfma16(b0, a, acc[m][0]);   // D[col][row]
        acc[m][1] = mfma16(b1f, a, acc[m][1]);
      }
    }
    const int ncg = p >> 1;
    const float sc = (ncg == 0) ? 0.17677669529663687f : 1.0f;
    short* dst = qkv + ((size_t)ncg * mtot + (size_t)blockIdx.x * 64) * 256;
    #pragma unroll
    for (int n2 = 0; n2 < 2; ++n2) {
      int colg = p * 128 + w * 32 + n2 * 16 + hi4;
      float4 bbv = *(const float4*)(qbp + colg);
      int c255 = colg & 255;
      #pragma unroll
      for (int m = 0; m < 4; ++m) {
        int row = m * 16 + l15;
        s16x4 o;
        o[0] = f2bf((acc[m][n2][0] + bbv.x) * sc);
        o[1] = f2bf((acc[m][n2][1] + bbv.y) * sc);
        o[2] = f2bf((acc[m][n2][2] + bbv.z) * sc);
        o[3] = f2bf((acc[m][n2][3] + bbv.w) * sc);
        *(s16x4*)(dst + (size_t)row * 256 + c255) = o;
      }
    }
  }
}

// ---------------- window attention: one block per (window, head) ----------------
__global__ __launch_bounds__(256, 4) void k_attn(
    const short* __restrict__ Q, const short* __restrict__ Kb,
    const short* __restrict__ V, short* __restrict__ O)
{
  __shared__ __align__(16) short Ks[64 * 72];
  __shared__ __align__(16) short VT[32 * 72];
  __shared__ __align__(16) short Ps[64 * 72];
  const int head = blockIdx.x & 7, win = blockIdx.x >> 3;
  const int tid = threadIdx.x, lane = tid & 63, w = tid >> 6;
  const int l15 = lane & 15, hi = lane >> 4, hi4 = hi * 4;
  const size_t base = (size_t)win * 16384 + head * 32;
  {
    int kk = tid >> 2, db = (tid & 3) * 8;
    s16x8 kv = *(const s16x8*)(Kb + base + (size_t)kk * 256 + db);
    *(s16x8*)&Ks[kk * 72 + db] = kv;
    s16x8 vv = *(const s16x8*)(V + base + (size_t)kk * 256 + db);
    #pragma unroll
    for (int i = 0; i < 8; ++i) VT[(db + i) * 72 + kk] = vv[i];
  }
  bf16x8 aq = *(const bf16x8*)(Q + base + (size_t)(w * 16 + l15) * 256 + hi * 8);
  __syncthreads();
  f32x4 zero = {0.f, 0.f, 0.f, 0.f};
  f32x4 s[4];
  #pragma unroll
  for (int t = 0; t < 4; ++t) {
    bf16x8 bk = *(const bf16x8*)&Ks[(t * 16 + l15) * 72 + hi * 8];
    s[t] = mfma16(aq, bk, zero);
  }
  float rs[4];
  #pragma unroll
  for (int j = 0; j < 4; ++j) {
    float m = fmaxf(fmaxf(s[0][j], s[1][j]), fmaxf(s[2][j], s[3][j]));
    #pragma unroll
    for (int mk = 1; mk < 16; mk <<= 1) m = fmaxf(m, __shfl_xor(m, mk));
    float sum = 0.f;
    #pragma unroll
    for (int t = 0; t < 4; ++t) { float p = __expf(s[t][j] - m); s[t][j] = p; sum += p; }
    #pragma unroll
    for (int mk = 1; mk < 16; mk <<= 1) sum += __shfl_xor(sum, mk);
    rs[j] = 1.f / sum;
  }
  #pragma unroll
  for (int t = 0; t < 4; ++t)
    #pragma unroll
    for (int j = 0; j < 4; ++j)
      Ps[(w * 16 + hi4 + j) * 72 + t * 16 + l15] = f2bf(s[t][j]);
  __syncthreads();
  f32x4 o[2] = {{0.f,0.f,0.f,0.f}, {0.f,0.f,0.f,0.f}};
  #pragma unroll
  for (int ks = 0; ks < 2; ++ks) {
    bf16x8 ap = *(const bf16x8*)&Ps[(w * 16 + l15) * 72 + ks * 32 + hi * 8];
    #pragma unroll
    for (int dt = 0; dt < 2; ++dt) {
      bf16x8 bv = *(const bf16x8*)&VT[(dt * 16 + l15) * 72 + ks * 32 + hi * 8];
      o[dt] = mfma16(ap, bv, o[dt]);
    }
  }
  #pragma unroll
  for (int dt = 0; dt < 2; ++dt)
    #pragma unroll
    for (int j = 0; j < 4; ++j)
      O[(size_t)(win * 64 + w * 16 + hi4 + j) * 256 + head * 32 + dt * 16 + l15] =
          f2bf(o[dt][j] * rs[j]);
}

// ---------------- proj + residual + LN2 (unchanged from R2) ----------------
__global__ __launch_bounds__(256, 4) void k_proj(
    const short* __restrict__ ao, const short* __restrict__ WprojT,
    const float* __restrict__ pb, const float* __restrict__ x,
    short* __restrict__ y2, short* __restrict__ hresb,
    const float* __restrict__ g2, const float* __restrict__ b2, int chunk_off)
{
  __shared__ __align__(16) short As[64 * 256];
  __shared__ float redS[64 * 4];
  __shared__ float redQ[64 * 4];
  const int tid = threadIdx.x, lane = tid & 63, w = tid >> 6;
  const int l15 = lane & 15, hi = lane >> 4, hi4 = hi * 4;
  const int bm0 = blockIdx.x * 64;
  {
    int r2 = lane >> 5, c8 = lane & 31;
    #pragma unroll
    for (int i = 0; i < 8; ++i) {
      int seg = w * 8 + i;
      int row = seg * 2 + r2;
      gload16(ao + (size_t)(bm0 + row) * 256 + ((c8 ^ (row & 7)) * 8), As + seg * 512);
    }
  }
  __syncthreads();
  const short* B0 = WprojT + (size_t)(w * 64 + l15) * 256 + hi * 8;
  bf16x8 bnx[4];
  #pragma unroll
  for (int n = 0; n < 4; ++n) bnx[n] = *(const bf16x8*)(B0 + n * 16 * 256);
  f32x4 acc[4][4] = {};
  #pragma unroll
  for (int kk = 0; kk < 8; ++kk) {
    bf16x8 bc[4] = {bnx[0], bnx[1], bnx[2], bnx[3]};
    if (kk < 7) {
      #pragma unroll
      for (int n = 0; n < 4; ++n)
        bnx[n] = *(const bf16x8*)(B0 + n * 16 * 256 + (kk + 1) * 32);
    }
    #pragma unroll
    for (int m = 0; m < 4; ++m) {
      int row = m * 16 + l15;
      bf16x8 a = *(const bf16x8*)(As + row * 256 + (((kk * 4 + hi) ^ (row & 7)) << 3));
      #pragma unroll
      for (int n = 0; n < 4; ++n) acc[m][n] = mfma16(a, bc[n], acc[m][n]);
    }
  }
  int srow[4][4];
  #pragma unroll
  for (int m = 0; m < 4; ++m)
    #pragma unroll
    for (int j = 0; j < 4; ++j) {
      int wrow = chunk_off + bm0 + m * 16 + hi4 + j;
      int bb = wrow >> 12, rem = wrow & 4095, win = rem >> 6, tok = rem & 63;
      int rsp = (tok >> 3) * 8 + (win >> 3);
      int csp = (tok & 7) * 8 + (win & 7);
      srow[m][j] = bb * 4096 + rsp * 64 + csp;
    }
  float s1[4][4] = {}, s2[4][4] = {};
  #pragma unroll
  for (int m = 0; m < 4; ++m)
    #pragma unroll
    for (int n = 0; n < 4; ++n) {
      int col = w * 64 + n * 16 + l15;
      float bia = pb[col];
      #pragma unroll
      for (int j = 0; j < 4; ++j) {
        float val = acc[m][n][j] + bia + x[(size_t)srow[m][j] * 256 + col];
        acc[m][n][j] = val;
        s1[m][j] += val; s2[m][j] += val * val;
      }
    }
  #pragma unroll
  for (int m = 0; m < 4; ++m)
    #pragma unroll
    for (int j = 0; j < 4; ++j) {
      float a = s1[m][j], bq = s2[m][j];
      #pragma unroll
      for (int mk = 1; mk < 16; mk <<= 1) { a += __shfl_xor(a, mk); bq += __shfl_xor(bq, mk); }
      s1[m][j] = a; s2[m][j] = bq;
    }
  if (l15 == 0) {
    #pragma unroll
    for (int m = 0; m < 4; ++m)
      #pragma unroll
      for (int j = 0; j < 4; ++j) {
        int rl = m * 16 + hi4 + j;
        redS[rl * 4 + w] = s1[m][j];
        redQ[rl * 4 + w] = s2[m][j];
      }
  }
  __syncthreads();
  #pragma unroll
  for (int m = 0; m < 4; ++m)
    #pragma unroll
    for (int j = 0; j < 4; ++j) {
      int rl = m * 16 + hi4 + j;
      float S = redS[rl * 4] + redS[rl * 4 + 1] + redS[rl * 4 + 2] + redS[rl * 4 + 3];
      float Qs = redQ[rl * 4] + redQ[rl * 4 + 1] + redQ[rl * 4 + 2] + redQ[rl * 4 + 3];
      float mean = S * (1.f / 256.f);
      float var  = Qs * (1.f / 256.f) - mean * mean;
      float rstd = rsqrtf(var + 1e-5f);
      int lrow = srow[m][j] - chunk_off;
      #pragma unroll
      for (int n = 0; n < 4; ++n) {
        int col = w * 64 + n * 16 + l15;
        float val = acc[m][n][j];
        hresb[(size_t)lrow * 256 + col] = f2bf(val);
        y2[(size_t)lrow * 256 + col] = f2bf((val - mean) * rstd * g2[col] + b2[col]);
      }
    }
}

// ---------------- fused MLP v3 ----------------
// 512 thr / 8 waves; swapped-operand MFMA; depth-4 rolling weight prefetch;
// P2 weight loads issued before GELU barrier; sigmoid-form GELU; b64 hs I/O.
__global__ __launch_bounds__(512, 4) void k_mlp(
    const short* __restrict__ y2, const short* __restrict__ hres,
    const short* __restrict__ W1T, const float* __restrict__ b1,
    const short* __restrict__ W2T, const float* __restrict__ b2,
    float* __restrict__ outp)
{
  __shared__ __align__(16) short As[64 * 256];
  __shared__ __align__(16) short hs[64 * 256];
  const int tid = threadIdx.x, lane = tid & 63, w = tid >> 6;   // 8 waves
  const int l15 = lane & 15, hi = lane >> 4, hi4 = hi * 4;
  const int bm0 = blockIdx.x * 64;
  {
    int r2 = lane >> 5, c8 = lane & 31;
    #pragma unroll
    for (int i = 0; i < 4; ++i) {
      int seg = w * 4 + i, row = seg * 2 + r2;
      gload16(y2 + (size_t)(bm0 + row) * 256 + ((c8 ^ (row & 7)) * 8), As + seg * 512);
    }
  }
  f32x4 oacc[4][2] = {};
  const short* B2base = W2T + (size_t)(w * 32 + l15) * 1024 + hi * 8;
  __syncthreads();
  for (int hc = 0; hc < 4; ++hc) {
    const short* B1 = W1T + (size_t)(hc * 256 + w * 32 + l15) * 256 + hi * 8;
    bf16x8 pre[8];
    #pragma unroll
    for (int kp = 0; kp < 4; ++kp) {
      pre[kp * 2 + 0] = *(const bf16x8*)(B1 + kp * 32);
      pre[kp * 2 + 1] = *(const bf16x8*)(B1 + 16 * 256 + kp * 32);
    }
    f32x4 acc1[4][2] = {};
    #pragma unroll
    for (int kk = 0; kk < 8; ++kk) {
      bf16x8 b0 = pre[(kk & 3) * 2], b1f = pre[(kk & 3) * 2 + 1];
      if (kk < 4) {
        pre[(kk & 3) * 2 + 0] = *(const bf16x8*)(B1 + (kk + 4) * 32);
        pre[(kk & 3) * 2 + 1] = *(const bf16x8*)(B1 + 16 * 256 + (kk + 4) * 32);
      }
      #pragma unroll
      for (int m = 0; m < 4; ++m) {
        int row = m * 16 + l15;
        bf16x8 a = *(const bf16x8*)(As + row * 256 + (((kk * 4 + hi) ^ (row & 7)) << 3));
        acc1[m][0] = mfma16(b0, a, acc1[m][0]);   // D[hcol][xrow]
        acc1[m][1] = mfma16(b1f, a, acc1[m][1]);
      }
    }
    // issue P2 weight loads early: latency hides under GELU + barriers
    const short* B2 = B2base + hc * 256;
    bf16x8 pre2[8];
    #pragma unroll
    for (int kp = 0; kp < 4; ++kp) {
      pre2[kp * 2 + 0] = *(const bf16x8*)(B2 + kp * 32);
      pre2[kp * 2 + 1] = *(const bf16x8*)(B2 + 16 * 1024 + kp * 32);
    }
    __syncthreads();   // previous P2 done reading hs
    #pragma unroll
    for (int m = 0; m < 4; ++m)
      #pragma unroll
      for (int n2 = 0; n2 < 2; ++n2) {
        int colb = w * 32 + n2 * 16 + hi4;
        int row = m * 16 + l15;
        float4 bbv = *(const float4*)(b1 + hc * 256 + colb);
        float bj[4] = {bbv.x, bbv.y, bbv.z, bbv.w};
        s16x4 o;
        #pragma unroll
        for (int j = 0; j < 4; ++j) {
          float vv = acc1[m][n2][j] + bj[j];
          float z = vv + 0.044715f * vv * vv * vv;
          float ge = vv / (1.f + __expf(-1.5957691216057308f * z));
          o[j] = f2bf(ge);
        }
        int c8 = colb >> 3;
        *(s16x4*)(hs + row * 256 + ((c8 ^ (row & 7)) << 3) + (hi & 1) * 4) = o;
      }
    __syncthreads();   // hs ready
    #pragma unroll
    for (int kk = 0; kk < 8; ++kk) {
      bf16x8 b0 = pre2[(kk & 3) * 2], b1f = pre2[(kk & 3) * 2 + 1];
      if (kk < 4) {
        pre2[(kk & 3) * 2 + 0] = *(const bf16x8*)(B2 + (kk + 4) * 32);
        pre2[(kk & 3) * 2 + 1] = *(const bf16x8*)(B2 + 16 * 1024 + (kk + 4) * 32);
      }
      #pragma unroll
      for (int m = 0; m < 4; ++m) {
        int row = m * 16 + l15;
        bf16x8 a = *(const bf16x8*)(hs + row * 256 + (((kk * 4 + hi) ^ (row & 7)) << 3));
        oacc[m][0] = mfma16(b0, a, oacc[m][0]);   // D[outcol][xrow]
        oacc[m][1] = mfma16(b1f, a, oacc[m][1]);
      }
    }
  }
  #pragma unroll
  for (int m = 0; m < 4; ++m)
    #pragma unroll
    for (int n2 = 0; n2 < 2; ++n2) {
      size_t row = (size_t)bm0 + m * 16 + l15;
      int colb = w * 32 + n2 * 16 + hi4;
      float4 bbv = *(const float4*)(b2 + colb);
      s16x4 hr = *(const s16x4*)(hres + row * 256 + colb);
      float4 ov;
      ov.x = oacc[m][n2][0] + bbv.x + bf2f(hr[0]);
      ov.y = oacc[m][n2][1] + bbv.y + bf2f(hr[1]);
      ov.z = oacc[m][n2][2] + bbv.z + bf2f(hr[2]);
      ov.w = oacc[m][n2][3] + bbv.w + bf2f(hr[3]);
      *(float4*)(outp + row * 256 + colb) = ov;
    }
}

// ---------------- host ----------------
extern "C" void kernel_launch(void* const* d_in, const int* in_sizes, int n_in,
                              void* d_out, int out_size, void* d_ws, size_t ws_size,
                              hipStream_t stream) {
  const float* x     = (const float*)d_in[0];
  const float* ln1g  = (const float*)d_in[1];
  const float* ln1b  = (const float*)d_in[2];
  const float* qkvw  = (const float*)d_in[3];
  const float* qkvb  = (const float*)d_in[4];
  const float* projw = (const float*)d_in[5];
  const float* projb = (const float*)d_in[6];
  const float* ln2g  = (const float*)d_in[7];
  const float* ln2b  = (const float*)d_in[8];
  const float* w1    = (const float*)d_in[9];
  const float* b1    = (const float*)d_in[10];
  const float* w2    = (const float*)d_in[11];
  const float* b2    = (const float*)d_in[12];
  float* out = (float*)d_out;
  char* ws = (char*)d_ws;

  const size_t MTOT = 131072;
  int nchunk;
  if (ws_size >= 4ull * MTOT * 512 + (2u << 20)) nchunk = 1;
  else if (ws_size >= 4ull * (MTOT / 2) * 512 + (2u << 20)) nchunk = 2;
  else nchunk = 4;
  const size_t M = MTOT / nchunk;
  const int nwin = (int)(M / 64);

  short* qkv = (short*)ws;
  short* y2b = (short*)ws;
  short* hrb = (short*)ws + M * 256;
  short* aob = (short*)ws + 3 * M * 256;
  char*  wreg = ws + 4ull * M * 512;
  short* WqkvT  = (short*)wreg;                      // 393,216 B
  short* WprojT = (short*)(wreg + 393216);           // 131,072 B
  short* W1T    = (short*)(wreg + 524288);           // 524,288 B
  short* W2T    = (short*)(wreg + 1048576);          // 524,288 B
  float* qkvbp  = (float*)(wreg + 1572864);          // 3,072 B

  k_prep_qkv<<<768, 256, 0, stream>>>(qkvw, qkvb, WqkvT, qkvbp);
  k_transpose<<<256, 256, 0, stream>>>(projw, WprojT, 256, 256);
  k_transpose<<<1024, 256, 0, stream>>>(w1, W1T, 256, 1024);
  k_transpose<<<1024, 256, 0, stream>>>(w2, W2T, 1024, 256);

  for (int c = 0; c < nchunk; ++c) {
    k_qkvln<<<nwin, 256, 0, stream>>>(x, ln1g, ln1b, WqkvT, qkvbp, qkv,
                                      c * nwin, (int)M);
    k_attn<<<nwin * 8, 256, 0, stream>>>(qkv, qkv + M * 256, qkv + 2 * M * 256, aob);
    k_proj<<<nwin, 256, 0, stream>>>(aob, WprojT, projb, x, y2b, hrb,
                                     ln2g, ln2b, (int)(c * M));
    k_mlp<<<nwin, 512, 0, stream>>>(y2b, hrb, W1T, b1, W2T, b2,
                                    out + (size_t)c * M * 256);
  }
}

// Round 5
// 582.671 us; speedup vs baseline: 1.4424x; 1.2740x over previous
//
#include <hip/hip_runtime.h>
#include <cstdint>

using bf16x8 = __attribute__((ext_vector_type(8))) __bf16;
using f32x4  = __attribute__((ext_vector_type(4))) float;
using s16x8  = __attribute__((ext_vector_type(8))) short;
using s16x4  = __attribute__((ext_vector_type(4))) short;

#define DI static __device__ __forceinline__

DI short f2bf(float f) {
  unsigned u = __float_as_uint(f);
  u = (u + 0x7fffu + ((u >> 16) & 1u)) >> 16;
  return (short)u;
}
DI float bf2f(short s) {
  return __uint_as_float(((unsigned)(unsigned short)s) << 16);
}

DI void gload16(const short* g, short* l) {
  __builtin_amdgcn_global_load_lds((const __attribute__((address_space(1))) unsigned*)g,
                                   (__attribute__((address_space(3))) unsigned*)l, 16, 0, 0);
}

DI f32x4 mfma16(bf16x8 a, bf16x8 b, f32x4 c) {
  return __builtin_amdgcn_mfma_f32_16x16x32_bf16(a, b, c, 0, 0, 0);
}

// Stage a [256 rows x 32 k] bf16 panel (16 KB) into LDS, XOR-swizzled.
// W points at panel row 0; rs = row stride (shorts); koff = k offset (shorts).
// Read back chunk hi of row r at: r*32 + ((hi ^ ((r^(r>>2))&3))*8).
template<int CALLS>
DI void stageW(const short* __restrict__ W, int rs, int koff, short* dst, int w, int lane) {
  #pragma unroll
  for (int i = 0; i < CALLS; ++i) {
    int idx = (w * CALLS + i) * 64 + lane;
    int row = idx >> 2, slot = idx & 3;
    gload16(W + (size_t)row * rs + koff + (slot ^ ((row ^ (row >> 2)) & 3)) * 8,
            dst + (w * CALLS + i) * 512);
  }
}

// ---------------- weight prep ----------------
__global__ void k_transpose(const float* __restrict__ src, short* __restrict__ dst,
                            int K, int N) {
  int idx = blockIdx.x * 256 + threadIdx.x;   // dst[n][k] = src[k][n]
  if (idx >= N * K) return;
  int n = idx / K, k = idx - n * K;
  dst[idx] = f2bf(src[(size_t)k * N + n]);
}

__global__ void k_prep_qkv(const float* __restrict__ w, const float* __restrict__ b,
                           short* __restrict__ wt, float* __restrict__ bp) {
  int idx = blockIdx.x * 256 + threadIdx.x;   // 768*256
  if (idx >= 768 * 256) return;
  int jn = idx >> 8;        // new col: q*256 + h*32 + d
  int k  = idx & 255;
  int q = jn >> 8, rest = jn & 255, h = rest >> 5, d = rest & 31;
  int jo = h * 96 + d * 3 + q;
  wt[idx] = f2bf(w[(size_t)k * 768 + jo]);
  if (k == 0) bp[jn] = b[jo];
}

// ---------------- QKV: fused LN1 + window gather + staged-weight GEMM ----------------
// 256 thr / 4 waves; M=64 (one window). 3 panels (Q,K,V) x 8 staged K-steps.
__global__ __launch_bounds__(256, 2) void k_qkvln(
    const float* __restrict__ x, const float* __restrict__ g1, const float* __restrict__ b1v,
    const short* __restrict__ WqkvT, const float* __restrict__ qbp,
    short* __restrict__ qkv, int win0, int mtot)
{
  __shared__ __align__(16) short As[64 * 256];      // 32 KB
  __shared__ __align__(16) short Ws[2][256 * 32];   // 2 x 16 KB
  const int tid = threadIdx.x, lane = tid & 63, w = tid >> 6;
  const int l15 = lane & 15, hi = lane >> 4, hi4 = hi * 4;
  const int wg = win0 + blockIdx.x;
  const int bb = wg >> 6, wl = wg & 63, wrr = wl >> 3, wcc = wl & 7;
  // stage first weight panel step while LN1 runs
  stageW<4>(WqkvT, 256, 0, &Ws[0][0], w, lane);
  // LN1 + window gather -> As (swizzled)
  #pragma unroll
  for (int p = 0; p < 4; ++p) {
    int tok = w * 16 + p * 4 + hi;
    int sr = bb * 4096 + ((tok >> 3) * 8 + wrr) * 64 + (tok & 7) * 8 + wcc;
    const float* xr = x + (size_t)sr * 256;
    float4 v[4];
    #pragma unroll
    for (int ii = 0; ii < 4; ++ii) v[ii] = *(const float4*)(xr + l15 * 4 + ii * 64);
    float s = 0.f, q = 0.f;
    #pragma unroll
    for (int ii = 0; ii < 4; ++ii) {
      s += v[ii].x + v[ii].y + v[ii].z + v[ii].w;
      q += v[ii].x * v[ii].x + v[ii].y * v[ii].y + v[ii].z * v[ii].z + v[ii].w * v[ii].w;
    }
    #pragma unroll
    for (int mk = 1; mk < 16; mk <<= 1) { s += __shfl_xor(s, mk); q += __shfl_xor(q, mk); }
    float mean = s * (1.f / 256.f);
    float var  = q * (1.f / 256.f) - mean * mean;
    float rstd = rsqrtf(var + 1e-5f);
    #pragma unroll
    for (int ii = 0; ii < 4; ++ii) {
      float4 gv = *(const float4*)(g1 + l15 * 4 + ii * 64);
      float4 bv = *(const float4*)(b1v + l15 * 4 + ii * 64);
      s16x4 o;
      o[0] = f2bf((v[ii].x - mean) * rstd * gv.x + bv.x);
      o[1] = f2bf((v[ii].y - mean) * rstd * gv.y + bv.y);
      o[2] = f2bf((v[ii].z - mean) * rstd * gv.z + bv.z);
      o[3] = f2bf((v[ii].w - mean) * rstd * gv.w + bv.w);
      int c8 = (l15 >> 1) + ii * 8;
      *(s16x4*)(As + tok * 256 + ((c8 ^ (tok & 7)) << 3) + (l15 & 1) * 4) = o;
    }
  }
  __syncthreads();   // drains As ds-writes AND Ws[0] gloads
  int cur = 0;
  for (int p = 0; p < 3; ++p) {
    f32x4 acc[4][4] = {};
    for (int s = 0; s < 8; ++s) {
      if (s < 7)       stageW<4>(WqkvT + (size_t)p * 256 * 256, 256, (s + 1) * 32, &Ws[cur ^ 1][0], w, lane);
      else if (p < 2)  stageW<4>(WqkvT + (size_t)(p + 1) * 256 * 256, 256, 0, &Ws[cur ^ 1][0], w, lane);
      bf16x8 af[4], wf[4];
      #pragma unroll
      for (int m = 0; m < 4; ++m) {
        int row = m * 16 + l15;
        af[m] = *(const bf16x8*)(As + row * 256 + (((s * 4 + hi) ^ (row & 7)) << 3));
      }
      #pragma unroll
      for (int n = 0; n < 4; ++n) {
        int rc = w * 64 + n * 16 + l15;
        wf[n] = *(const bf16x8*)(&Ws[cur][0] + rc * 32 + ((hi ^ ((rc ^ (rc >> 2)) & 3)) << 3));
      }
      #pragma unroll
      for (int m = 0; m < 4; ++m)
        #pragma unroll
        for (int n = 0; n < 4; ++n) acc[m][n] = mfma16(wf[n], af[m], acc[m][n]);  // D[col][xrow]
      cur ^= 1;
      __syncthreads();
    }
    const float sc = (p == 0) ? 0.17677669529663687f : 1.0f;
    short* dst = qkv + ((size_t)p * mtot + (size_t)blockIdx.x * 64) * 256;
    #pragma unroll
    for (int n = 0; n < 4; ++n) {
      int colg = w * 64 + n * 16 + hi4;
      float4 bbv = *(const float4*)(qbp + p * 256 + colg);
      #pragma unroll
      for (int m = 0; m < 4; ++m) {
        int row = m * 16 + l15;
        s16x4 o;
        o[0] = f2bf((acc[m][n][0] + bbv.x) * sc);
        o[1] = f2bf((acc[m][n][1] + bbv.y) * sc);
        o[2] = f2bf((acc[m][n][2] + bbv.z) * sc);
        o[3] = f2bf((acc[m][n][3] + bbv.w) * sc);
        *(s16x4*)(dst + (size_t)row * 256 + colg) = o;
      }
    }
  }
}

// ---------------- window attention (unchanged) ----------------
__global__ __launch_bounds__(256, 4) void k_attn(
    const short* __restrict__ Q, const short* __restrict__ Kb,
    const short* __restrict__ V, short* __restrict__ O)
{
  __shared__ __align__(16) short Ks[64 * 72];
  __shared__ __align__(16) short VT[32 * 72];
  __shared__ __align__(16) short Ps[64 * 72];
  const int head = blockIdx.x & 7, win = blockIdx.x >> 3;
  const int tid = threadIdx.x, lane = tid & 63, w = tid >> 6;
  const int l15 = lane & 15, hi = lane >> 4, hi4 = hi * 4;
  const size_t base = (size_t)win * 16384 + head * 32;
  {
    int kk = tid >> 2, db = (tid & 3) * 8;
    s16x8 kv = *(const s16x8*)(Kb + base + (size_t)kk * 256 + db);
    *(s16x8*)&Ks[kk * 72 + db] = kv;
    s16x8 vv = *(const s16x8*)(V + base + (size_t)kk * 256 + db);
    #pragma unroll
    for (int i = 0; i < 8; ++i) VT[(db + i) * 72 + kk] = vv[i];
  }
  bf16x8 aq = *(const bf16x8*)(Q + base + (size_t)(w * 16 + l15) * 256 + hi * 8);
  __syncthreads();
  f32x4 zero = {0.f, 0.f, 0.f, 0.f};
  f32x4 s[4];
  #pragma unroll
  for (int t = 0; t < 4; ++t) {
    bf16x8 bk = *(const bf16x8*)&Ks[(t * 16 + l15) * 72 + hi * 8];
    s[t] = mfma16(aq, bk, zero);
  }
  float rs[4];
  #pragma unroll
  for (int j = 0; j < 4; ++j) {
    float m = fmaxf(fmaxf(s[0][j], s[1][j]), fmaxf(s[2][j], s[3][j]));
    #pragma unroll
    for (int mk = 1; mk < 16; mk <<= 1) m = fmaxf(m, __shfl_xor(m, mk));
    float sum = 0.f;
    #pragma unroll
    for (int t = 0; t < 4; ++t) { float p = __expf(s[t][j] - m); s[t][j] = p; sum += p; }
    #pragma unroll
    for (int mk = 1; mk < 16; mk <<= 1) sum += __shfl_xor(sum, mk);
    rs[j] = 1.f / sum;
  }
  #pragma unroll
  for (int t = 0; t < 4; ++t)
    #pragma unroll
    for (int j = 0; j < 4; ++j)
      Ps[(w * 16 + hi4 + j) * 72 + t * 16 + l15] = f2bf(s[t][j]);
  __syncthreads();
  f32x4 o[2] = {{0.f,0.f,0.f,0.f}, {0.f,0.f,0.f,0.f}};
  #pragma unroll
  for (int ks = 0; ks < 2; ++ks) {
    bf16x8 ap = *(const bf16x8*)&Ps[(w * 16 + l15) * 72 + ks * 32 + hi * 8];
    #pragma unroll
    for (int dt = 0; dt < 2; ++dt) {
      bf16x8 bv = *(const bf16x8*)&VT[(dt * 16 + l15) * 72 + ks * 32 + hi * 8];
      o[dt] = mfma16(ap, bv, o[dt]);
    }
  }
  #pragma unroll
  for (int dt = 0; dt < 2; ++dt)
    #pragma unroll
    for (int j = 0; j < 4; ++j)
      O[(size_t)(win * 64 + w * 16 + hi4 + j) * 256 + head * 32 + dt * 16 + l15] =
          f2bf(o[dt][j] * rs[j]);
}

// ---------------- proj + residual + LN2: staged weights ----------------
__global__ __launch_bounds__(256, 2) void k_proj(
    const short* __restrict__ ao, const short* __restrict__ WprojT,
    const float* __restrict__ pb, const float* __restrict__ x,
    short* __restrict__ y2, short* __restrict__ hresb,
    const float* __restrict__ g2, const float* __restrict__ b2, int chunk_off)
{
  __shared__ __align__(16) short As[64 * 256];      // 32 KB
  __shared__ __align__(16) short Ws[2][256 * 32];   // 2 x 16 KB (reused as red arrays)
  const int tid = threadIdx.x, lane = tid & 63, w = tid >> 6;
  const int l15 = lane & 15, hi = lane >> 4, hi4 = hi * 4;
  const int bm0 = blockIdx.x * 64;
  stageW<4>(WprojT, 256, 0, &Ws[0][0], w, lane);
  {
    int r2 = lane >> 5, c8 = lane & 31;
    #pragma unroll
    for (int i = 0; i < 8; ++i) {
      int seg = w * 8 + i;
      int row = seg * 2 + r2;
      gload16(ao + (size_t)(bm0 + row) * 256 + ((c8 ^ (row & 7)) * 8), As + seg * 512);
    }
  }
  __syncthreads();
  int cur = 0;
  f32x4 acc[4][4] = {};
  for (int s = 0; s < 8; ++s) {
    if (s < 7) stageW<4>(WprojT, 256, (s + 1) * 32, &Ws[cur ^ 1][0], w, lane);
    bf16x8 af[4], bfr[4];
    #pragma unroll
    for (int m = 0; m < 4; ++m) {
      int row = m * 16 + l15;
      af[m] = *(const bf16x8*)(As + row * 256 + (((s * 4 + hi) ^ (row & 7)) << 3));
    }
    #pragma unroll
    for (int n = 0; n < 4; ++n) {
      int rc = w * 64 + n * 16 + l15;
      bfr[n] = *(const bf16x8*)(&Ws[cur][0] + rc * 32 + ((hi ^ ((rc ^ (rc >> 2)) & 3)) << 3));
    }
    #pragma unroll
    for (int m = 0; m < 4; ++m)
      #pragma unroll
      for (int n = 0; n < 4; ++n) acc[m][n] = mfma16(af[m], bfr[n], acc[m][n]);  // unswapped
    cur ^= 1;
    __syncthreads();
  }
  // epilogue (unchanged): + bias + x residual, LN2 stats, write hres + y2
  float* redS = (float*)&Ws[0][0];
  float* redQ = redS + 64 * 4;
  int srow[4][4];
  #pragma unroll
  for (int m = 0; m < 4; ++m)
    #pragma unroll
    for (int j = 0; j < 4; ++j) {
      int wrow = chunk_off + bm0 + m * 16 + hi4 + j;
      int bb = wrow >> 12, rem = wrow & 4095, win = rem >> 6, tok = rem & 63;
      int rsp = (tok >> 3) * 8 + (win >> 3);
      int csp = (tok & 7) * 8 + (win & 7);
      srow[m][j] = bb * 4096 + rsp * 64 + csp;
    }
  float s1[4][4] = {}, s2[4][4] = {};
  #pragma unroll
  for (int m = 0; m < 4; ++m)
    #pragma unroll
    for (int n = 0; n < 4; ++n) {
      int col = w * 64 + n * 16 + l15;
      float bia = pb[col];
      #pragma unroll
      for (int j = 0; j < 4; ++j) {
        float val = acc[m][n][j] + bia + x[(size_t)srow[m][j] * 256 + col];
        acc[m][n][j] = val;
        s1[m][j] += val; s2[m][j] += val * val;
      }
    }
  #pragma unroll
  for (int m = 0; m < 4; ++m)
    #pragma unroll
    for (int j = 0; j < 4; ++j) {
      float a = s1[m][j], bq = s2[m][j];
      #pragma unroll
      for (int mk = 1; mk < 16; mk <<= 1) { a += __shfl_xor(a, mk); bq += __shfl_xor(bq, mk); }
      s1[m][j] = a; s2[m][j] = bq;
    }
  if (l15 == 0) {
    #pragma unroll
    for (int m = 0; m < 4; ++m)
      #pragma unroll
      for (int j = 0; j < 4; ++j) {
        int rl = m * 16 + hi4 + j;
        redS[rl * 4 + w] = s1[m][j];
        redQ[rl * 4 + w] = s2[m][j];
      }
  }
  __syncthreads();
  #pragma unroll
  for (int m = 0; m < 4; ++m)
    #pragma unroll
    for (int j = 0; j < 4; ++j) {
      int rl = m * 16 + hi4 + j;
      float S = redS[rl * 4] + redS[rl * 4 + 1] + redS[rl * 4 + 2] + redS[rl * 4 + 3];
      float Qs = redQ[rl * 4] + redQ[rl * 4 + 1] + redQ[rl * 4 + 2] + redQ[rl * 4 + 3];
      float mean = S * (1.f / 256.f);
      float var  = Qs * (1.f / 256.f) - mean * mean;
      float rstd = rsqrtf(var + 1e-5f);
      int lrow = srow[m][j] - chunk_off;
      #pragma unroll
      for (int n = 0; n < 4; ++n) {
        int col = w * 64 + n * 16 + l15;
        float val = acc[m][n][j];
        hresb[(size_t)lrow * 256 + col] = f2bf(val);
        y2[(size_t)lrow * 256 + col] = f2bf((val - mean) * rstd * g2[col] + b2[col]);
      }
    }
}

// ---------------- fused MLP v4: staged weights, dynamic LDS 128 KB ----------------
// 512 thr / 8 waves (2M x 4N), M=128. LDS: As 64K | Ws 2x16K | hs 32K.
__global__ __launch_bounds__(512, 2) void k_mlp(
    const short* __restrict__ y2, const short* __restrict__ hres,
    const short* __restrict__ W1T, const float* __restrict__ b1,
    const short* __restrict__ W2T, const float* __restrict__ b2,
    float* __restrict__ outp)
{
  extern __shared__ __align__(16) char dsm[];
  short* As = (short*)dsm;                   // [128][256] swizzled
  short* Wb = (short*)(dsm + 65536);         // 2 x [panel] 16 KB
  short* hs = (short*)(dsm + 98304);         // [128][128] swizzled (16-slot)
  const int tid = threadIdx.x, lane = tid & 63, w = tid >> 6;
  const int l15 = lane & 15, hi = lane >> 4, hi4 = hi * 4;
  const int wm = w >> 2, wn = w & 3;
  const int bm0 = blockIdx.x * 128;
  // stage As (64 KB) + W1 phase0 step0
  {
    #pragma unroll
    for (int i = 0; i < 8; ++i) {
      int idx = (w * 8 + i) * 64 + lane;
      int row = idx >> 5, c = idx & 31;
      int sc = (c & 24) | ((c & 7) ^ (row & 7));
      gload16(y2 + (size_t)(bm0 + row) * 256 + sc * 8, As + (w * 8 + i) * 512);
    }
    #pragma unroll
    for (int i = 0; i < 2; ++i) {           // W1 step: [128 hcol][64 k] 16 KB
      int idx = (w * 2 + i) * 64 + lane;
      int row = idx >> 3, slot = idx & 7;
      gload16(W1T + (size_t)row * 256 + (slot ^ (row & 7)) * 8, Wb + (w * 2 + i) * 512);
    }
  }
  f32x4 oacc[4][4] = {};
  __syncthreads();
  int cur = 0;
  for (int hc = 0; hc < 8; ++hc) {
    f32x4 acc1[4][2] = {};
    for (int s = 0; s < 4; ++s) {           // ---- P1 steps (BK=64)
      short* nxt = Wb + (cur ^ 1) * 8192;
      if (s < 3) {
        #pragma unroll
        for (int i = 0; i < 2; ++i) {
          int idx = (w * 2 + i) * 64 + lane;
          int row = idx >> 3, slot = idx & 7;
          gload16(W1T + (size_t)(hc * 128 + row) * 256 + (s + 1) * 64 + (slot ^ (row & 7)) * 8,
                  nxt + (w * 2 + i) * 512);
        }
      } else {                              // W2(hc, step0): [256 outcol][32 hk]
        #pragma unroll
        for (int i = 0; i < 2; ++i) {
          int idx = (w * 2 + i) * 64 + lane;
          int row = idx >> 2, slot = idx & 3;
          gload16(W2T + (size_t)row * 1024 + hc * 128 + (slot ^ ((row ^ (row >> 2)) & 3)) * 8,
                  nxt + (w * 2 + i) * 512);
        }
      }
      const short* Wc = Wb + cur * 8192;
      #pragma unroll
      for (int q = 0; q < 2; ++q) {
        int kk = s * 2 + q;
        bf16x8 af[4], wf[2];
        #pragma unroll
        for (int m = 0; m < 4; ++m) {
          int row = wm * 64 + m * 16 + l15;
          af[m] = *(const bf16x8*)(As + row * 256 + (((kk * 4 + hi) ^ (row & 7)) << 3));
        }
        #pragma unroll
        for (int n2 = 0; n2 < 2; ++n2) {
          int rc = wn * 32 + n2 * 16 + l15;
          wf[n2] = *(const bf16x8*)(Wc + rc * 64 + (((q * 4 + hi) ^ (rc & 7)) << 3));
        }
        #pragma unroll
        for (int m = 0; m < 4; ++m) {
          acc1[m][0] = mfma16(wf[0], af[m], acc1[m][0]);   // D[hcol][xrow]
          acc1[m][1] = mfma16(wf[1], af[m], acc1[m][1]);
        }
      }
      cur ^= 1;
      __syncthreads();
    }
    // GELU -> hs  (acc1[m][n2][j] = h[xrow=wm*64+m*16+l15][hcol=wn*32+n2*16+hi4+j])
    #pragma unroll
    for (int m = 0; m < 4; ++m)
      #pragma unroll
      for (int n2 = 0; n2 < 2; ++n2) {
        int xrow = wm * 64 + m * 16 + l15;
        int hcolb = wn * 32 + n2 * 16 + hi4;
        float4 bbv = *(const float4*)(b1 + hc * 128 + hcolb);
        float bj[4] = {bbv.x, bbv.y, bbv.z, bbv.w};
        s16x4 o;
        #pragma unroll
        for (int j = 0; j < 4; ++j) {
          float vv = acc1[m][n2][j] + bj[j];
          float z = vv + 0.044715f * vv * vv * vv;
          o[j] = f2bf(vv / (1.f + __expf(-1.5957691216057308f * z)));
        }
        int chunk = hcolb >> 3;
        *(s16x4*)(hs + xrow * 128 + ((chunk ^ (xrow & 15)) << 3) + (hi & 1) * 4) = o;
      }
    __syncthreads();
    for (int s = 0; s < 4; ++s) {           // ---- P2 steps (BK=32)
      short* nxt = Wb + (cur ^ 1) * 8192;
      if (s < 3) {
        #pragma unroll
        for (int i = 0; i < 2; ++i) {
          int idx = (w * 2 + i) * 64 + lane;
          int row = idx >> 2, slot = idx & 3;
          gload16(W2T + (size_t)row * 1024 + hc * 128 + (s + 1) * 32 +
                      (slot ^ ((row ^ (row >> 2)) & 3)) * 8,
                  nxt + (w * 2 + i) * 512);
        }
      } else if (hc < 7) {                  // W1(hc+1, step0)
        #pragma unroll
        for (int i = 0; i < 2; ++i) {
          int idx = (w * 2 + i) * 64 + lane;
          int row = idx >> 3, slot = idx & 7;
          gload16(W1T + (size_t)((hc + 1) * 128 + row) * 256 + (slot ^ (row & 7)) * 8,
                  nxt + (w * 2 + i) * 512);
        }
      }
      const short* Wc = Wb + cur * 8192;
      bf16x8 hf[4], w2f[4];
      #pragma unroll
      for (int m = 0; m < 4; ++m) {
        int xr = wm * 64 + m * 16 + l15;
        hf[m] = *(const bf16x8*)(hs + xr * 128 + (((s * 4 + hi) ^ (xr & 15)) << 3));
      }
      #pragma unroll
      for (int n = 0; n < 4; ++n) {
        int rc = wn * 64 + n * 16 + l15;
        w2f[n] = *(const bf16x8*)(Wc + rc * 32 + ((hi ^ ((rc ^ (rc >> 2)) & 3)) << 3));
      }
      #pragma unroll
      for (int m = 0; m < 4; ++m)
        #pragma unroll
        for (int n = 0; n < 4; ++n)
          oacc[m][n] = mfma16(w2f[n], hf[m], oacc[m][n]);   // D[outcol][xrow]
      cur ^= 1;
      __syncthreads();
    }
  }
  // epilogue: oacc[m][n][j] = out[xrow=wm*64+m*16+l15][outcol=wn*64+n*16+hi4+j]
  #pragma unroll
  for (int m = 0; m < 4; ++m)
    #pragma unroll
    for (int n = 0; n < 4; ++n) {
      size_t row = (size_t)bm0 + wm * 64 + m * 16 + l15;
      int colb = wn * 64 + n * 16 + hi4;
      float4 bbv = *(const float4*)(b2 + colb);
      s16x4 hr = *(const s16x4*)(hres + row * 256 + colb);
      float4 ov;
      ov.x = oacc[m][n][0] + bbv.x + bf2f(hr[0]);
      ov.y = oacc[m][n][1] + bbv.y + bf2f(hr[1]);
      ov.z = oacc[m][n][2] + bbv.z + bf2f(hr[2]);
      ov.w = oacc[m][n][3] + bbv.w + bf2f(hr[3]);
      *(float4*)(outp + row * 256 + colb) = ov;
    }
}

// ---------------- host ----------------
extern "C" void kernel_launch(void* const* d_in, const int* in_sizes, int n_in,
                              void* d_out, int out_size, void* d_ws, size_t ws_size,
                              hipStream_t stream) {
  const float* x     = (const float*)d_in[0];
  const float* ln1g  = (const float*)d_in[1];
  const float* ln1b  = (const float*)d_in[2];
  const float* qkvw  = (const float*)d_in[3];
  const float* qkvb  = (const float*)d_in[4];
  const float* projw = (const float*)d_in[5];
  const float* projb = (const float*)d_in[6];
  const float* ln2g  = (const float*)d_in[7];
  const float* ln2b  = (const float*)d_in[8];
  const float* w1    = (const float*)d_in[9];
  const float* b1    = (const float*)d_in[10];
  const float* w2    = (const float*)d_in[11];
  const float* b2    = (const float*)d_in[12];
  float* out = (float*)d_out;
  char* ws = (char*)d_ws;

  static int mlp_attr_set = 0;
  if (!mlp_attr_set) {
    hipFuncSetAttribute((const void*)k_mlp,
                        hipFuncAttributeMaxDynamicSharedMemorySize, 131072);
    mlp_attr_set = 1;
  }

  const size_t MTOT = 131072;
  int nchunk;
  if (ws_size >= 4ull * MTOT * 512 + (2u << 20)) nchunk = 1;
  else if (ws_size >= 4ull * (MTOT / 2) * 512 + (2u << 20)) nchunk = 2;
  else nchunk = 4;
  const size_t M = MTOT / nchunk;
  const int nwin = (int)(M / 64);

  short* qkv = (short*)ws;
  short* y2b = (short*)ws;
  short* hrb = (short*)ws + M * 256;
  short* aob = (short*)ws + 3 * M * 256;
  char*  wreg = ws + 4ull * M * 512;
  short* WqkvT  = (short*)wreg;                      // 393,216 B
  short* WprojT = (short*)(wreg + 393216);           // 131,072 B
  short* W1T    = (short*)(wreg + 524288);           // 524,288 B
  short* W2T    = (short*)(wreg + 1048576);          // 524,288 B
  float* qkvbp  = (float*)(wreg + 1572864);          // 3,072 B

  k_prep_qkv<<<768, 256, 0, stream>>>(qkvw, qkvb, WqkvT, qkvbp);
  k_transpose<<<256, 256, 0, stream>>>(projw, WprojT, 256, 256);
  k_transpose<<<1024, 256, 0, stream>>>(w1, W1T, 256, 1024);
  k_transpose<<<1024, 256, 0, stream>>>(w2, W2T, 1024, 256);

  for (int c = 0; c < nchunk; ++c) {
    k_qkvln<<<nwin, 256, 0, stream>>>(x, ln1g, ln1b, WqkvT, qkvbp, qkv,
                                      c * nwin, (int)M);
    k_attn<<<nwin * 8, 256, 0, stream>>>(qkv, qkv + M * 256, qkv + 2 * M * 256, aob);
    k_proj<<<nwin, 256, 0, stream>>>(aob, WprojT, projb, x, y2b, hrb,
                                     ln2g, ln2b, (int)(c * M));
    k_mlp<<<(int)(M / 128), 512, 131072, stream>>>(y2b, hrb, W1T, b1, W2T, b2,
                                                   out + (size_t)c * M * 256);
  }
}